// Round 6
// baseline (341.549 us; speedup 1.0000x reference)
//
#include <hip/hip_runtime.h>
#include <hip/hip_bf16.h>

typedef _Float16 f16x8 __attribute__((ext_vector_type(8)));
typedef _Float16 f16x4 __attribute__((ext_vector_type(4)));
typedef float f32x4 __attribute__((ext_vector_type(4)));

#define B_SZ 64
#define T_SZ 2048
#define D_SZ 300
#define M_SZ (B_SZ * T_SZ)      // 131072
#define KP 320                   // padded K for W
#define NP 640                   // padded combined N (z: 0..299, o: 320..619)
#define NCHUNK 32
#define CLEN 64                  // T / NCHUNK

__device__ __forceinline__ void gld_lds16(const void* g, void* l) {
    __builtin_amdgcn_global_load_lds(
        (const __attribute__((address_space(1))) unsigned int*)g,
        (__attribute__((address_space(3))) unsigned int*)l,
        16, 0, 0);
}

__device__ __forceinline__ float fast_tanh(float x) {
    float e = __expf(2.0f * x);
    return 1.0f - 2.0f * __builtin_amdgcn_rcpf(e + 1.0f);
}

// ---- pack Wz/Wo fp32 [300,300] -> combined fp16 [640,320], zero-padded ----
// The k-pad zeros (k 300..319) also nullify the garbage A reads in the K-tail.
__global__ void pack_w(const float* __restrict__ Wz, const float* __restrict__ Wo,
                       _Float16* __restrict__ W) {
    unsigned int i = blockIdx.x * 256u + threadIdx.x;
    if (i >= NP * KP) return;
    unsigned int n = i / KP;
    unsigned int k = i - n * KP;
    float v = 0.0f;
    if (k < D_SZ) {
        if (n < D_SZ) v = Wz[n * D_SZ + k];
        else if (n >= 320 && n < 320 + D_SZ) v = Wo[(n - 320) * D_SZ + k];
    }
    W[i] = (_Float16)v;
}

__global__ void pack_bias(const float* __restrict__ bz, const float* __restrict__ bo,
                          float* __restrict__ bias) {
    int n = threadIdx.x;
    float v = 0.0f;
    if (n < D_SZ) v = bz[n];
    else if (n >= 320 && n < 320 + D_SZ) v = bo[n - 320];
    bias[n] = v;
}

__device__ __forceinline__ f16x8 cvt8(f32x4 v0, f32x4 v1) {
    f16x8 r;
    r[0] = (_Float16)v0[0]; r[1] = (_Float16)v0[1];
    r[2] = (_Float16)v0[2]; r[3] = (_Float16)v0[3];
    r[4] = (_Float16)v1[0]; r[5] = (_Float16)v1[1];
    r[6] = (_Float16)v1[2]; r[7] = (_Float16)v1[3];
    return r;
}

// ---- GEMM: C16[m][n] = tanh( sum_k X[m][k]*W[n][k] + bias[n] ), fp16 out ----
// 128x128 tile, BK=32, 4 waves (2x2). A reg-staged from fp32 X (load -> cvt ->
// ds_write_b128) into the PROVEN conflict-free f16 layout (64B rows,
// unit ^ ((row>>1)&3)). B staged via global_load_lds. One barrier per K-step.
// LDS 32KB -> up to 5 blocks/CU; occupancy is the lever this round.
__global__ __launch_bounds__(256, 4) void gemm_zo(const float* __restrict__ X,
                                                  const _Float16* __restrict__ W,
                                                  const float* __restrict__ bias,
                                                  _Float16* __restrict__ C) {
    __shared__ _Float16 As[2][128 * 32];   // 8 KB each
    __shared__ _Float16 Bs[2][128 * 32];

    const int tid = threadIdx.x;
    const int lane = tid & 63;
    const int wid = tid >> 6;              // 0..3
    const int wm = wid >> 1, wn = wid & 1;

    // XCD-aware swizzle (5120 blocks, 5120 % 8 == 0 -> bijective); the 5
    // bn-tiles of one bm are consecutive on one XCD -> A reuse is L2-resident.
    int g = blockIdx.x;
    int s = (g & 7) * (5120 / 8) + (g >> 3);
    int bm = s / 5;          // 1024 M-tiles
    int bn = s - bm * 5;     // 5 N-tiles

    const int l15 = lane & 15;
    const int kq = lane >> 4;

    f32x4 acc[4][4] = {};

    // ---- A reg-staging assignment: thread t covers row ar = t>>1, two 16B
    // units {au, au+1} (au = (t&1)*2) of the 64B f16 row.
    const int ar = tid >> 1;
    const int au = (tid & 1) * 2;
    const float* asrc = X + (size_t)(bm * 128 + ar) * D_SZ;
    const int aswz = (ar >> 1) & 3;
    _Float16* adst0 = &As[0][ar * 32 + (au ^ aswz) * 8];
    _Float16* adst1 = &As[0][ar * 32 + ((au + 1) ^ aswz) * 8];

    // ---- B staging via gld_lds: chunks of 16 rows (16 x 64B = 1KB); wave
    // stages chunks wid, wid+4. Source unit pre-swizzled.
    const int brow_in = lane >> 2;
    const int bsrc_u = (lane & 3) ^ ((brow_in >> 1) & 3);

    auto stageB = [&](int buf, int kt) {
#pragma unroll
        for (int j = 0; j < 2; ++j) {
            int c = wid + j * 4;
            int row = c * 16 + brow_in;
            gld_lds16(W + (size_t)(bn * 128 + row) * KP + kt * 32 + bsrc_u * 8,
                      &Bs[buf][c * 512]);
        }
    };

    f32x4 av[4];
    auto loadA = [&](int kt) {
        int k0 = kt * 32 + au * 8;
        if (kt < 9) {
#pragma unroll
            for (int j = 0; j < 4; ++j) av[j] = *(const f32x4*)(asrc + k0 + j * 4);
        } else {
            // tail: k >= 300 reads would cross into the next row (and OOB on
            // the very last row). Zero them; W's k-pad zeros match.
#pragma unroll
            for (int j = 0; j < 4; ++j) {
                int k = k0 + j * 4;
                av[j] = (k < D_SZ) ? *(const f32x4*)(asrc + k) : f32x4{};
            }
        }
    };
    auto writeA = [&](int buf) {
        *(f16x8*)(adst0 + buf * 128 * 32) = cvt8(av[0], av[1]);
        *(f16x8*)(adst1 + buf * 128 * 32) = cvt8(av[2], av[3]);
    };

    // prologue
    loadA(0);
    stageB(0, 0);
    writeA(0);
    __syncthreads();

    int buf = 0;
#pragma unroll 1
    for (int kt = 0; kt < 10; ++kt) {
        if (kt < 9) {
            loadA(kt + 1);          // issue global loads early (hide under MFMA)
            stageB(buf ^ 1, kt + 1);
        }

        f16x8 bf[4], af[4];
#pragma unroll
        for (int ns = 0; ns < 4; ++ns) {
            int row = wn * 64 + ns * 16 + l15;
            int u = kq ^ ((row >> 1) & 3);
            bf[ns] = *(const f16x8*)&Bs[buf][row * 32 + u * 8];
        }
#pragma unroll
        for (int ms = 0; ms < 4; ++ms) {
            int row = wm * 64 + ms * 16 + l15;
            int u = kq ^ ((row >> 1) & 3);
            af[ms] = *(const f16x8*)&As[buf][row * 32 + u * 8];
        }

        __builtin_amdgcn_s_setprio(1);
#pragma unroll
        for (int ms = 0; ms < 4; ++ms)
#pragma unroll
            for (int ns = 0; ns < 4; ++ns)
                acc[ms][ns] = __builtin_amdgcn_mfma_f32_16x16x32_f16(bf[ns], af[ms], acc[ms][ns], 0, 0, 0);
        __builtin_amdgcn_s_setprio(0);

        if (kt < 9) writeA(buf ^ 1);   // cvt + ds_write after MFMA issue

        __syncthreads();
        buf ^= 1;
    }

    // epilogue: swapped layout -> lane holds 4 consecutive n at one m.
    // m = mrow0 + ms*16 + l15; n = ncol0 + ns*16 + kq*4 + r
    const int mrow0 = bm * 128 + wm * 64;
    const int ncol0 = bn * 128 + wn * 64;
#pragma unroll
    for (int ns = 0; ns < 4; ++ns) {
        int nb = ncol0 + ns * 16 + kq * 4;
        f32x4 b4 = *(const f32x4*)&bias[nb];
#pragma unroll
        for (int ms = 0; ms < 4; ++ms) {
            int m = mrow0 + ms * 16 + l15;
            f16x4 v;
#pragma unroll
            for (int r = 0; r < 4; ++r)
                v[r] = (_Float16)fast_tanh(acc[ms][ns][r] + b4[r]);
            *(f16x4*)&C[(size_t)m * NP + nb] = v;
        }
    }
}

// ---- scan phase 1: per (b, chunk, d) compute affine (A = prod g, Bc) ----
__global__ void scan_p1(const float* __restrict__ gate, const _Float16* __restrict__ C,
                        float* __restrict__ Aout, float* __restrict__ Bout) {
    int b = blockIdx.x >> 5;
    int nc = blockIdx.x & 31;
    int d = threadIdx.x;
    if (d >= D_SZ) return;
    size_t base = (size_t)b * T_SZ + (size_t)nc * CLEN;
    const float* gp = gate + base * D_SZ + d;
    const _Float16* zp = C + base * NP + d;
    float A = 1.0f, Bc = 0.0f;
    for (int t = 0; t < CLEN; ++t) {
        float gv = gp[(size_t)t * D_SZ];
        float zv = (float)zp[(size_t)t * NP];
        A *= gv;
        Bc = gv * Bc + (1.0f - gv) * zv;
    }
    int o = (b * NCHUNK + nc) * D_SZ + d;
    Aout[o] = A;
    Bout[o] = Bc;
}

// ---- scan phase 2: sequential scan over the 32 chunk summaries ----
__global__ void scan_p2(const float* __restrict__ A, const float* __restrict__ Bc,
                        float* __restrict__ Cin) {
    int idx = blockIdx.x * 256 + threadIdx.x;
    if (idx >= B_SZ * D_SZ) return;
    int b = idx / D_SZ;
    int d = idx - b * D_SZ;
    float c = 0.0f;
    for (int nc = 0; nc < NCHUNK; ++nc) {
        int o = (b * NCHUNK + nc) * D_SZ + d;
        Cin[o] = c;
        c = A[o] * c + Bc[o];
    }
}

// ---- scan phase 3: replay chunk with correct c_in, write h = o * c ----
__global__ void scan_p3(const float* __restrict__ gate, const _Float16* __restrict__ C,
                        const float* __restrict__ Cin, float* __restrict__ out) {
    int b = blockIdx.x >> 5;
    int nc = blockIdx.x & 31;
    int d = threadIdx.x;
    if (d >= D_SZ) return;
    size_t base = (size_t)b * T_SZ + (size_t)nc * CLEN;
    const float* gp = gate + base * D_SZ + d;
    const _Float16* zp = C + base * NP + d;
    const _Float16* op = zp + 320;
    float* hp = out + base * D_SZ + d;
    float c = Cin[(b * NCHUNK + nc) * D_SZ + d];
    for (int t = 0; t < CLEN; ++t) {
        float gv = gp[(size_t)t * D_SZ];
        float zv = (float)zp[(size_t)t * NP];
        float ov = (float)op[(size_t)t * NP];
        c = gv * c + (1.0f - gv) * zv;
        hp[(size_t)t * D_SZ] = ov * c;
    }
}

extern "C" void kernel_launch(void* const* d_in, const int* in_sizes, int n_in,
                              void* d_out, int out_size, void* d_ws, size_t ws_size,
                              hipStream_t stream) {
    const float* gate = (const float*)d_in[0];
    const float* xin  = (const float*)d_in[1];
    const float* Wz   = (const float*)d_in[2];
    const float* bz   = (const float*)d_in[3];
    const float* Wo   = (const float*)d_in[4];
    const float* bo   = (const float*)d_in[5];
    float* out = (float*)d_out;

    char* ws = (char*)d_ws;
    _Float16* C16  = (_Float16*)(ws);                       // M*NP*2      = 167,772,160
    _Float16* Wc   = (_Float16*)(ws + 167772160ull);        // NP*KP*2     = 409,600
    float*    bias = (float*)   (ws + 168181760ull);        // NP*4        = 2,560
    float*    Ach  = (float*)   (ws + 168184320ull);        // 64*32*300*4 = 2,457,600
    float*    Bch  = (float*)   (ws + 170641920ull);        // 2,457,600
    float*    Cin  = (float*)   (ws + 173099520ull);        // 2,457,600

    pack_w<<<(NP * KP + 255) / 256, 256, 0, stream>>>(Wz, Wo, Wc);
    pack_bias<<<1, NP, 0, stream>>>(bz, bo, bias);

    gemm_zo<<<(M_SZ / 128) * (NP / 128), 256, 0, stream>>>(xin, Wc, bias, C16);

    scan_p1<<<B_SZ * NCHUNK, 320, 0, stream>>>(gate, C16, Ach, Bch);
    scan_p2<<<(B_SZ * D_SZ + 255) / 256, 256, 0, stream>>>(Ach, Bch, Cin);
    scan_p3<<<B_SZ * NCHUNK, 320, 0, stream>>>(gate, C16, Cin, out);
}